// Round 1
// baseline (99.266 us; speedup 1.0000x reference)
//
#include <hip/hip_runtime.h>
#include <math.h>

#define EPSF     1e-12f
#define INV_4PI  0.07957747154594767f
#define LOG2E    1.4426950408889634f

typedef float v2f __attribute__((ext_vector_type(2)));

#if __has_builtin(__builtin_elementwise_fma)
#define FMA2(a, b, c) __builtin_elementwise_fma((a), (b), (c))
#else
#define FMA2(a, b, c) ((a) * (b) + (c))
#endif

__device__ __forceinline__ v2f bcast(float x) { v2f r; r.x = x; r.y = x; return r; }

// packed exp2 via deg-5 Taylor on [-0.5,0.5] + ldexp.
// Rationale: v_exp_f32 is ~16 cyc/wave-inst on the (serial-additive) trans
// pipe; this poly is ~12 packed/scalar VALU instrs per TWO exps (~24 cyc),
// and frees the trans pipe entirely. rel err <= 2.4e-6 (next Taylor term).
// Arg range here is ~[-70, +15] (Z <= zapprox(0.9) ~ 10), so rndne/cvt/ldexp
// are all safely in range; large-negative args flush to 0 via ldexp.
__device__ __forceinline__ v2f exp2p(v2f x) {
    v2f n; n.x = __builtin_rintf(x.x); n.y = __builtin_rintf(x.y);
    v2f r = x - n;
    const v2f c1 = bcast(0.69314718056f);
    const v2f c2 = bcast(0.24022650700f);
    const v2f c3 = bcast(0.05550410866f);
    const v2f c4 = bcast(0.00961812911f);
    const v2f c5 = bcast(0.00133335581f);
    v2f p = FMA2(FMA2(FMA2(FMA2(FMA2(c5, r, c4), r, c3), r, c2), r, c1), r, bcast(1.0f));
    v2f o;
    o.x = ldexpf(p.x, (int)n.x);
    o.y = ldexpf(p.y, (int)n.y);
    return o;
}

// Z = z_approxbis(f), f already clipped to [0, 0.999999]
__device__ __forceinline__ float zapprox(float f) {
    float f2 = f * f;
    float f4 = f2 * f2;
    float f6 = f4 * f2;
    float f8 = f4 * f4;
    float denom = 3.0f - 1.00651f * f2 - 0.962251f * f4 + 1.47353f * f6 - 0.48953f * f8;
    denom = fmaxf(denom, EPSF);
    float p = 1.0f - 2.0f * (1.0f - f) * (1.0f + 1.01524f * f) / denom;
    return 2.0f * f / fmaxf(1.0f - p, 1e-6f);
}

// z / sinh(z), z >= 0
__device__ __forceinline__ float z_over_sinh(float z) {
    float zz = z * z;
    float series = 1.0f - zz / 6.0f + zz * zz / 120.0f;
    float E = __expf(z);
    float s = 0.5f * (E - 1.0f / E);
    float r = z / s;           // NaN at z==0, discarded by select
    return (z < 1e-4f) ? series : r;
}

// per-species: g(dir) = 2^(zx*dx + zy*dy + zz*dz + la)
__device__ __forceinline__ float4 setup_spec(float N, float Fx, float Fy, float Fz) {
    N = fmaxf(N, EPSF);
    float nf = sqrtf(Fx * Fx + Fy * Fy + Fz * Fz);
    float f  = fminf(fmaxf(nf / N, 0.0f), 0.999999f);
    float Z  = zapprox(f);
    float A  = N * INV_4PI * z_over_sinh(Z);
    float sc = Z * LOG2E / fmaxf(nf, EPSF);
    return make_float4(Fx * sc, Fy * sc, Fz * sc, log2f(A));
}

// ---- kernel 1: per-(batch,species) Spec precompute -> d_ws --------------
__global__ __launch_bounds__(256) void spec_kernel(
    const float* __restrict__ F4, float4* __restrict__ ws, int B)
{
    int t = blockIdx.x * blockDim.x + threadIdx.x;
    if (t >= 4 * B) return;
    int b = t >> 2, s = t & 3;
    const float4* row = (const float4*)(F4 + (size_t)b * 24);
    float N, Fx, Fy, Fz;
    if (s == 0) {                       // e
        float4 a = row[0];  N = a.w; Fx = a.x; Fy = a.y; Fz = a.z;
    } else if (s == 1) {                // ebar
        float4 a = row[3];  N = a.w; Fx = a.x; Fy = a.y; Fz = a.z;
    } else if (s == 2) {                // x = mean(flavors 1,2) of nu
        float4 a = row[1], c = row[2];
        N = 0.5f * (a.w + c.w); Fx = 0.5f * (a.x + c.x);
        Fy = 0.5f * (a.y + c.y); Fz = 0.5f * (a.z + c.z);
    } else {                            // xbar
        float4 a = row[4], c = row[5];
        N = 0.5f * (a.w + c.w); Fx = 0.5f * (a.x + c.x);
        Fy = 0.5f * (a.y + c.y); Fz = 0.5f * (a.z + c.z);
    }
    ws[(size_t)b * 4 + s] = setup_spec(N, Fx, Fy, Fz);
}

// ---- kernel 2: hot quadrature loop --------------------------------------
// Antipodal restructure: the 20x40 midpoint grid is exactly antipodal —
// dir d in [0,400) pairs with -d (at dir (19-i)*40+(j+20)%40) at EQUAL
// weight. We fold log2(w) into the exponent (base = la + lw), so
//   t(+q) = zx*qx+zy*qy+zz*qz + base,   t(-q) = 2*base - t(+q)   [1 FMA]
// and the exp output is pre-weighted: all qw multiplies disappear, masked
// terms are pure cndmask. Moments of the antipode use the s/d trick:
//   acc0 += (a+b);  acc1..3 += (a-b)*q.
// exp2 is the deg-5 poly above (trans pipe is serial-additive with VALU;
// poly is ~25% cheaper per exp AND packable).
// 8 lanes per batch, 32 batches per 256-thread block: 200 pair-pairs / 8
// lanes = 25 clean iterations, grid = B/32 = 1024 blocks = exactly 4
// resident blocks/CU at <=128 VGPR.
__global__ __launch_bounds__(256, 4) void box3d_kernel(
    const float4* __restrict__ ws,
    const float* __restrict__ dxp, const float* __restrict__ dyp,
    const float* __restrict__ dzp, const float* __restrict__ qwp,
    float* __restrict__ out, int B, int ndir)
{
    // pair-pair interleaved LDS: entry m covers antipodal pairs d0=2m, d1=2m+1
    //   sAB[m] = (qx0,qx1, qy0,qy1)   sCD[m] = (qz0,qz1, lw0,lw1)
    __shared__ float4 sAB[200], sCD[200];
    const int npp = ndir >> 2;               // 200 pair-pairs
    for (int m = threadIdx.x; m < npp; m += blockDim.x) {
        int d0 = 2 * m, d1 = d0 + 1;
        sAB[m] = make_float4(dxp[d0], dxp[d1], dyp[d0], dyp[d1]);
        sCD[m] = make_float4(dzp[d0], dzp[d1], __log2f(qwp[d0]), __log2f(qwp[d1]));
    }
    __syncthreads();

    const int sub = threadIdx.x & 7;         // lane within 8-group
    const int b = blockIdx.x * 32 + (threadIdx.x >> 3);
    if (b >= B) return;

    // specs precomputed by spec_kernel
    const float4* wsb = ws + (size_t)b * 4;
    float4 f0 = wsb[0], f1 = wsb[1], f2 = wsb[2], f3 = wsb[3];
    v2f zx0 = bcast(f0.x), zy0 = bcast(f0.y), zz0 = bcast(f0.z), la0 = bcast(f0.w);
    v2f zx1 = bcast(f1.x), zy1 = bcast(f1.y), zz1 = bcast(f1.z), la1 = bcast(f1.w);
    v2f zx2 = bcast(f2.x), zy2 = bcast(f2.y), zz2 = bcast(f2.z), la2 = bcast(f2.w);
    v2f zx3 = bcast(f3.x), zy3 = bcast(f3.y), zz3 = bcast(f3.z), la3 = bcast(f3.w);

    const v2f zero = bcast(0.0f);
    const v2f two  = bcast(2.0f);
    v2f aut0 = zero, aut1 = zero, aut2 = zero, aut3 = zero;
    v2f aup0 = zero, aup1 = zero, aup2 = zero, aup3 = zero;
    v2f avt0 = zero, avt1 = zero, avt2 = zero, avt3 = zero;
    v2f avp0 = zero, avp1 = zero, avp2 = zero, avp3 = zero;
    v2f agx0 = zero, agx1 = zero, agx2 = zero, agx3 = zero;
    v2f agy0 = zero, agy1 = zero, agy2 = zero, agy3 = zero;

    #pragma clang loop unroll(disable)
    for (int m = sub; m < npp; m += 8) {
        float4 ab = sAB[m];
        float4 cd = sCD[m];
        v2f qx; qx.x = ab.x; qx.y = ab.y;
        v2f qy; qy.x = ab.z; qy.y = ab.w;
        v2f qz; qz.x = cd.x; qz.y = cd.y;
        v2f lw; lw.x = cd.z; lw.y = cd.w;

        v2f b0 = la0 + lw, b1 = la1 + lw, b2 = la2 + lw, b3 = la3 + lw;
        v2f t0 = FMA2(zx0, qx, FMA2(zy0, qy, FMA2(zz0, qz, b0)));
        v2f t1 = FMA2(zx1, qx, FMA2(zy1, qy, FMA2(zz1, qz, b1)));
        v2f t2 = FMA2(zx2, qx, FMA2(zy2, qy, FMA2(zz2, qz, b2)));
        v2f t3 = FMA2(zx3, qx, FMA2(zy3, qy, FMA2(zz3, qz, b3)));
        v2f n0 = FMA2(two, b0, -t0);         // antipode exponent: 2*base - t
        v2f n1 = FMA2(two, b1, -t1);
        v2f n2 = FMA2(two, b2, -t2);
        v2f n3 = FMA2(two, b3, -t3);

        v2f gp0 = exp2p(t0), gp1 = exp2p(t1), gp2 = exp2p(t2), gp3 = exp2p(t3);
        v2f gn0 = exp2p(n0), gn1 = exp2p(n1), gn2 = exp2p(n2), gn3 = exp2p(n3);

        // weighted u = w*(g0-g2), v = w*(g1-g3) at +q and -q
        v2f uP = gp0 - gp2, vP = gp1 - gp3;
        v2f uN = gn0 - gn2, vN = gn1 - gn3;

        // masks (delta >= 0 <=> u >= v since w > 0); pure selects, no muls
        v2f suP, svP, suN, svN;
        suP.x = (uP.x >= vP.x) ? uP.x : 0.0f;  suP.y = (uP.y >= vP.y) ? uP.y : 0.0f;
        svP.x = (uP.x >= vP.x) ? vP.x : 0.0f;  svP.y = (uP.y >= vP.y) ? vP.y : 0.0f;
        suN.x = (uN.x >= vN.x) ? uN.x : 0.0f;  suN.y = (uN.y >= vN.y) ? uN.y : 0.0f;
        svN.x = (uN.x >= vN.x) ? vN.x : 0.0f;  svN.y = (uN.y >= vN.y) ? vN.y : 0.0f;

        // moments: +q contributes (a, a*q), -q contributes (b, -b*q)
        v2f s, d;
        s = uP + uN;   d = uP - uN;
        aut0 += s; aut1 = FMA2(d, qx, aut1); aut2 = FMA2(d, qy, aut2); aut3 = FMA2(d, qz, aut3);
        s = suP + suN; d = suP - suN;
        aup0 += s; aup1 = FMA2(d, qx, aup1); aup2 = FMA2(d, qy, aup2); aup3 = FMA2(d, qz, aup3);
        s = vP + vN;   d = vP - vN;
        avt0 += s; avt1 = FMA2(d, qx, avt1); avt2 = FMA2(d, qy, avt2); avt3 = FMA2(d, qz, avt3);
        s = svP + svN; d = svP - svN;
        avp0 += s; avp1 = FMA2(d, qx, avp1); avp2 = FMA2(d, qy, avp2); avp3 = FMA2(d, qz, avp3);
        s = gp2 + gn2; d = gp2 - gn2;
        agx0 += s; agx1 = FMA2(d, qx, agx1); agx2 = FMA2(d, qy, agx2); agx3 = FMA2(d, qz, agx3);
        s = gp3 + gn3; d = gp3 - gn3;
        agy0 += s; agy1 = FMA2(d, qx, agy1); agy2 = FMA2(d, qy, agy2); agy3 = FMA2(d, qz, agy3);
    }

    // ---- collapse packed halves, then butterfly over the 8-lane group ----
    float ut0 = aut0.x + aut0.y, ut1 = aut1.x + aut1.y, ut2 = aut2.x + aut2.y, ut3 = aut3.x + aut3.y;
    float up0 = aup0.x + aup0.y, up1 = aup1.x + aup1.y, up2 = aup2.x + aup2.y, up3 = aup3.x + aup3.y;
    float vt0 = avt0.x + avt0.y, vt1 = avt1.x + avt1.y, vt2 = avt2.x + avt2.y, vt3 = avt3.x + avt3.y;
    float vp0 = avp0.x + avp0.y, vp1 = avp1.x + avp1.y, vp2 = avp2.x + avp2.y, vp3 = avp3.x + avp3.y;
    float gx0 = agx0.x + agx0.y, gx1 = agx1.x + agx1.y, gx2 = agx2.x + agx2.y, gx3 = agx3.x + agx3.y;
    float gy0 = agy0.x + agy0.y, gy1 = agy1.x + agy1.y, gy2 = agy2.x + agy2.y, gy3 = agy3.x + agy3.y;

    #pragma unroll
    for (int msk = 1; msk <= 4; msk <<= 1) {
        ut0 += __shfl_xor(ut0, msk);  ut1 += __shfl_xor(ut1, msk);
        ut2 += __shfl_xor(ut2, msk);  ut3 += __shfl_xor(ut3, msk);
        up0 += __shfl_xor(up0, msk);  up1 += __shfl_xor(up1, msk);
        up2 += __shfl_xor(up2, msk);  up3 += __shfl_xor(up3, msk);
        vt0 += __shfl_xor(vt0, msk);  vt1 += __shfl_xor(vt1, msk);
        vt2 += __shfl_xor(vt2, msk);  vt3 += __shfl_xor(vt3, msk);
        vp0 += __shfl_xor(vp0, msk);  vp1 += __shfl_xor(vp1, msk);
        vp2 += __shfl_xor(vp2, msk);  vp3 += __shfl_xor(vp3, msk);
        gx0 += __shfl_xor(gx0, msk);  gx1 += __shfl_xor(gx1, msk);
        gx2 += __shfl_xor(gx2, msk);  gx3 += __shfl_xor(gx3, msk);
        gy0 += __shfl_xor(gy0, msk);  gy1 += __shfl_xor(gy1, msk);
        gy2 += __shfl_xor(gy2, msk);  gy3 += __shfl_xor(gy3, msk);
    }

    // Iplus = sum_{delta>=0} w*delta = up0 - vp0 (identical masked sums)
    // Iminus = Iplus - sum w*delta
    float ip = fmaxf(up0 - vp0, 0.0f);
    float im = fmaxf(ip - ut0 + vt0, 0.0f);

    float Ips = fmaxf(ip, EPSF), Ims = fmaxf(im, EPSF);
    const float third = 1.0f / 3.0f;
    float cp, cn;
    if (ip < im) {
        cp = third;
        cn = fminf(fmaxf(1.0f - (2.0f / 3.0f) * (Ips / Ims), 0.0f), 1.0f);
    } else {
        cp = fminf(fmaxf(1.0f - (2.0f / 3.0f) * (Ims / Ips), 0.0f), 1.0f);
        cn = third;
    }

    // ---- final moments: P = cp*up + cn*(ut-up); out per reference layout ----
    float P0 = cp * up0 + cn * (ut0 - up0), Q0 = cp * vp0 + cn * (vt0 - vp0);
    float P1 = cp * up1 + cn * (ut1 - up1), Q1 = cp * vp1 + cn * (vt1 - vp1);
    float P2 = cp * up2 + cn * (ut2 - up2), Q2 = cp * vp2 + cn * (vt2 - vp2);
    float P3 = cp * up3 + cn * (ut3 - up3), Q3 = cp * vp3 + cn * (vt3 - vp3);

    // memory layout per batch (6 float4): [e, x, x, ebar, xbar, xbar], each (Fx,Fy,Fz,N)
    float4* o4 = (float4*)out + (size_t)b * 6;
    if (sub == 0) {
        o4[0] = make_float4(gx1 + P1, gx2 + P2, gx3 + P3, gx0 + P0);                       // e
    } else if (sub == 1) {
        o4[1] = make_float4(gx1 + 0.5f * (ut1 - P1), gx2 + 0.5f * (ut2 - P2),
                            gx3 + 0.5f * (ut3 - P3), gx0 + 0.5f * (ut0 - P0));             // x
    } else if (sub == 2) {
        o4[2] = make_float4(gx1 + 0.5f * (ut1 - P1), gx2 + 0.5f * (ut2 - P2),
                            gx3 + 0.5f * (ut3 - P3), gx0 + 0.5f * (ut0 - P0));             // x
    } else if (sub == 3) {
        o4[3] = make_float4(gy1 + Q1, gy2 + Q2, gy3 + Q3, gy0 + Q0);                       // ebar
    } else if (sub == 4) {
        o4[4] = make_float4(gy1 + 0.5f * (vt1 - Q1), gy2 + 0.5f * (vt2 - Q2),
                            gy3 + 0.5f * (vt3 - Q3), gy0 + 0.5f * (vt0 - Q0));             // xbar
    } else if (sub == 5) {
        o4[5] = make_float4(gy1 + 0.5f * (vt1 - Q1), gy2 + 0.5f * (vt2 - Q2),
                            gy3 + 0.5f * (vt3 - Q3), gy0 + 0.5f * (vt0 - Q0));             // xbar
    } else if (sub == 6) {
        out[(size_t)B * 24 + b] = sqrtf(fmaxf(ip * im, 0.0f));                             // growth
    }
}

extern "C" void kernel_launch(void* const* d_in, const int* in_sizes, int n_in,
                              void* d_out, int out_size, void* d_ws, size_t ws_size,
                              hipStream_t stream) {
    const float* F4 = (const float*)d_in[0];
    const float* dx = (const float*)d_in[1];
    const float* dy = (const float*)d_in[2];
    const float* dz = (const float*)d_in[3];
    const float* qw = (const float*)d_in[4];
    float* out = (float*)d_out;

    int B = in_sizes[0] / 24;     // (B, 2, 3, 4)
    int ndir = in_sizes[1];       // 800
    float4* ws = (float4*)d_ws;   // B*4 float4 specs (2 MB at B=32768)

    int t1 = 4 * B;
    spec_kernel<<<(t1 + 255) / 256, 256, 0, stream>>>(F4, ws, B);
    int blocks = (B + 31) / 32;   // 32 batch elements per 256-thread block
    box3d_kernel<<<blocks, 256, 0, stream>>>(ws, dx, dy, dz, qw, out, B, ndir);
}

// Round 2
// 90.862 us; speedup vs baseline: 1.0925x; 1.0925x over previous
//
#include <hip/hip_runtime.h>
#include <math.h>

#define EPSF     1e-12f
#define INV_4PI  0.07957747154594767f
#define LOG2E    1.4426950408889634f

typedef float v2f __attribute__((ext_vector_type(2)));

#if __has_builtin(__builtin_elementwise_fma)
#define FMA2(a, b, c) __builtin_elementwise_fma((a), (b), (c))
#else
#define FMA2(a, b, c) ((a) * (b) + (c))
#endif

// hardware exp2: single v_exp_f32 per element. R1 post-mortem: the packed
// deg-5 poly replacement scalarized (rndne/cvt/ldexp have no packed forms)
// into ~2x the VALU issue volume and LOST 6 us despite freeing the trans
// pipe. 1 instr/exp is the issue-volume floor; keep the hw unit.
__device__ __forceinline__ v2f EXP2V(v2f t) {
    v2f r;
    r.x = __builtin_amdgcn_exp2f(t.x);
    r.y = __builtin_amdgcn_exp2f(t.y);
    return r;
}

__device__ __forceinline__ v2f bcast(float x) { v2f r; r.x = x; r.y = x; return r; }

// Z = z_approxbis(f), f already clipped to [0, 0.999999]
__device__ __forceinline__ float zapprox(float f) {
    float f2 = f * f;
    float f4 = f2 * f2;
    float f6 = f4 * f2;
    float f8 = f4 * f4;
    float denom = 3.0f - 1.00651f * f2 - 0.962251f * f4 + 1.47353f * f6 - 0.48953f * f8;
    denom = fmaxf(denom, EPSF);
    float p = 1.0f - 2.0f * (1.0f - f) * (1.0f + 1.01524f * f) / denom;
    return 2.0f * f / fmaxf(1.0f - p, 1e-6f);
}

// z / sinh(z), z >= 0
__device__ __forceinline__ float z_over_sinh(float z) {
    float zz = z * z;
    float series = 1.0f - zz / 6.0f + zz * zz / 120.0f;
    float E = __expf(z);
    float s = 0.5f * (E - 1.0f / E);
    float r = z / s;           // NaN at z==0, discarded by select
    return (z < 1e-4f) ? series : r;
}

// per-species: g(dir) = 2^(zx*dx + zy*dy + zz*dz + la)
__device__ __forceinline__ float4 setup_spec(float N, float Fx, float Fy, float Fz) {
    N = fmaxf(N, EPSF);
    float nf = sqrtf(Fx * Fx + Fy * Fy + Fz * Fz);
    float f  = fminf(fmaxf(nf / N, 0.0f), 0.999999f);
    float Z  = zapprox(f);
    float A  = N * INV_4PI * z_over_sinh(Z);
    float sc = Z * LOG2E / fmaxf(nf, EPSF);
    return make_float4(Fx * sc, Fy * sc, Fz * sc, log2f(A));
}

// ---- kernel 1: per-(batch,species) Spec precompute -> d_ws --------------
__global__ __launch_bounds__(256) void spec_kernel(
    const float* __restrict__ F4, float4* __restrict__ ws, int B)
{
    int t = blockIdx.x * blockDim.x + threadIdx.x;
    if (t >= 4 * B) return;
    int b = t >> 2, s = t & 3;
    const float4* row = (const float4*)(F4 + (size_t)b * 24);
    float N, Fx, Fy, Fz;
    if (s == 0) {                       // e
        float4 a = row[0];  N = a.w; Fx = a.x; Fy = a.y; Fz = a.z;
    } else if (s == 1) {                // ebar
        float4 a = row[3];  N = a.w; Fx = a.x; Fy = a.y; Fz = a.z;
    } else if (s == 2) {                // x = mean(flavors 1,2) of nu
        float4 a = row[1], c = row[2];
        N = 0.5f * (a.w + c.w); Fx = 0.5f * (a.x + c.x);
        Fy = 0.5f * (a.y + c.y); Fz = 0.5f * (a.z + c.z);
    } else {                            // xbar
        float4 a = row[4], c = row[5];
        N = 0.5f * (a.w + c.w); Fx = 0.5f * (a.x + c.x);
        Fy = 0.5f * (a.y + c.y); Fz = 0.5f * (a.z + c.z);
    }
    ws[(size_t)b * 4 + s] = setup_spec(N, Fx, Fy, Fz);
}

// ---- kernel 2: hot quadrature loop --------------------------------------
// Antipodal structure (verified R1): dirs 0..399 (theta rows i<10) each pair
// with a unique antipode at equal weight, so the 800-dir sum is
// sum_{d<400} w_d [f(+q_d) + f(-q_d)]. log2(w) folded into the exponent:
//   t(+q) = z.q + base,   t(-q) = 2*base - t   [1 FMA]
// exp output is pre-weighted (no qw muls; masks are pure cndmask); antipode
// moments via s/d trick: acc0 += (a+b), acc1..3 += (a-b)*q.
//
// R1 post-mortem fixes:
//  * hw v_exp_f32 restored (see EXP2V).
//  * occupancy: 16 lanes/batch, 16 batches/block -> 2048 blocks = 8
//    blocks/CU = 8 waves/SIMD at VGPR~60 (R1's 32-batch grid hard-capped
//    residency at 4 waves/SIMD, OccupancyPercent 25.6). Lanes sub<8 run 13
//    iters, sub>=8 run 12 (~4% exec-mask waste, paid for 2x residency).
__global__ __launch_bounds__(256, 4) void box3d_kernel(
    const float4* __restrict__ ws,
    const float* __restrict__ dxp, const float* __restrict__ dyp,
    const float* __restrict__ dzp, const float* __restrict__ qwp,
    float* __restrict__ out, int B, int ndir)
{
    // pair-pair interleaved LDS: entry m covers antipodal pairs d0=2m, d1=2m+1
    //   sAB[m] = (qx0,qx1, qy0,qy1)   sCD[m] = (qz0,qz1, lw0,lw1)
    __shared__ float4 sAB[200], sCD[200];
    const int npp = ndir >> 2;               // 200 pair-pairs
    for (int m = threadIdx.x; m < npp; m += blockDim.x) {
        int d0 = 2 * m, d1 = d0 + 1;
        sAB[m] = make_float4(dxp[d0], dxp[d1], dyp[d0], dyp[d1]);
        sCD[m] = make_float4(dzp[d0], dzp[d1], __log2f(qwp[d0]), __log2f(qwp[d1]));
    }
    __syncthreads();

    const int sub = threadIdx.x & 15;        // lane within 16-group
    const int b = blockIdx.x * 16 + (threadIdx.x >> 4);
    if (b >= B) return;

    // specs precomputed by spec_kernel
    const float4* wsb = ws + (size_t)b * 4;
    float4 f0 = wsb[0], f1 = wsb[1], f2 = wsb[2], f3 = wsb[3];
    v2f zx0 = bcast(f0.x), zy0 = bcast(f0.y), zz0 = bcast(f0.z), la0 = bcast(f0.w);
    v2f zx1 = bcast(f1.x), zy1 = bcast(f1.y), zz1 = bcast(f1.z), la1 = bcast(f1.w);
    v2f zx2 = bcast(f2.x), zy2 = bcast(f2.y), zz2 = bcast(f2.z), la2 = bcast(f2.w);
    v2f zx3 = bcast(f3.x), zy3 = bcast(f3.y), zz3 = bcast(f3.z), la3 = bcast(f3.w);

    const v2f zero = bcast(0.0f);
    const v2f two  = bcast(2.0f);
    v2f aut0 = zero, aut1 = zero, aut2 = zero, aut3 = zero;
    v2f aup0 = zero, aup1 = zero, aup2 = zero, aup3 = zero;
    v2f avt0 = zero, avt1 = zero, avt2 = zero, avt3 = zero;
    v2f avp0 = zero, avp1 = zero, avp2 = zero, avp3 = zero;
    v2f agx0 = zero, agx1 = zero, agx2 = zero, agx3 = zero;
    v2f agy0 = zero, agy1 = zero, agy2 = zero, agy3 = zero;

    #pragma clang loop unroll(disable)
    for (int m = sub; m < npp; m += 16) {
        float4 ab = sAB[m];
        float4 cd = sCD[m];
        v2f qx; qx.x = ab.x; qx.y = ab.y;
        v2f qy; qy.x = ab.z; qy.y = ab.w;
        v2f qz; qz.x = cd.x; qz.y = cd.y;
        v2f lw; lw.x = cd.z; lw.y = cd.w;

        v2f b0 = la0 + lw, b1 = la1 + lw, b2 = la2 + lw, b3 = la3 + lw;
        v2f t0 = FMA2(zx0, qx, FMA2(zy0, qy, FMA2(zz0, qz, b0)));
        v2f t1 = FMA2(zx1, qx, FMA2(zy1, qy, FMA2(zz1, qz, b1)));
        v2f t2 = FMA2(zx2, qx, FMA2(zy2, qy, FMA2(zz2, qz, b2)));
        v2f t3 = FMA2(zx3, qx, FMA2(zy3, qy, FMA2(zz3, qz, b3)));
        v2f n0 = FMA2(two, b0, -t0);         // antipode exponent: 2*base - t
        v2f n1 = FMA2(two, b1, -t1);
        v2f n2 = FMA2(two, b2, -t2);
        v2f n3 = FMA2(two, b3, -t3);

        v2f gp0 = EXP2V(t0), gp1 = EXP2V(t1), gp2 = EXP2V(t2), gp3 = EXP2V(t3);
        v2f gn0 = EXP2V(n0), gn1 = EXP2V(n1), gn2 = EXP2V(n2), gn3 = EXP2V(n3);

        // weighted u = w*(g0-g2), v = w*(g1-g3) at +q and -q
        v2f uP = gp0 - gp2, vP = gp1 - gp3;
        v2f uN = gn0 - gn2, vN = gn1 - gn3;

        // masks (delta >= 0 <=> u >= v since w > 0); pure selects, no muls
        v2f suP, svP, suN, svN;
        suP.x = (uP.x >= vP.x) ? uP.x : 0.0f;  suP.y = (uP.y >= vP.y) ? uP.y : 0.0f;
        svP.x = (uP.x >= vP.x) ? vP.x : 0.0f;  svP.y = (uP.y >= vP.y) ? vP.y : 0.0f;
        suN.x = (uN.x >= vN.x) ? uN.x : 0.0f;  suN.y = (uN.y >= vN.y) ? uN.y : 0.0f;
        svN.x = (uN.x >= vN.x) ? vN.x : 0.0f;  svN.y = (uN.y >= vN.y) ? vN.y : 0.0f;

        // moments: +q contributes (a, a*q), -q contributes (b, -b*q)
        v2f s, d;
        s = uP + uN;   d = uP - uN;
        aut0 += s; aut1 = FMA2(d, qx, aut1); aut2 = FMA2(d, qy, aut2); aut3 = FMA2(d, qz, aut3);
        s = suP + suN; d = suP - suN;
        aup0 += s; aup1 = FMA2(d, qx, aup1); aup2 = FMA2(d, qy, aup2); aup3 = FMA2(d, qz, aup3);
        s = vP + vN;   d = vP - vN;
        avt0 += s; avt1 = FMA2(d, qx, avt1); avt2 = FMA2(d, qy, avt2); avt3 = FMA2(d, qz, avt3);
        s = svP + svN; d = svP - svN;
        avp0 += s; avp1 = FMA2(d, qx, avp1); avp2 = FMA2(d, qy, avp2); avp3 = FMA2(d, qz, avp3);
        s = gp2 + gn2; d = gp2 - gn2;
        agx0 += s; agx1 = FMA2(d, qx, agx1); agx2 = FMA2(d, qy, agx2); agx3 = FMA2(d, qz, agx3);
        s = gp3 + gn3; d = gp3 - gn3;
        agy0 += s; agy1 = FMA2(d, qx, agy1); agy2 = FMA2(d, qy, agy2); agy3 = FMA2(d, qz, agy3);
    }

    // ---- collapse packed halves, then butterfly over the 16-lane group ----
    float ut0 = aut0.x + aut0.y, ut1 = aut1.x + aut1.y, ut2 = aut2.x + aut2.y, ut3 = aut3.x + aut3.y;
    float up0 = aup0.x + aup0.y, up1 = aup1.x + aup1.y, up2 = aup2.x + aup2.y, up3 = aup3.x + aup3.y;
    float vt0 = avt0.x + avt0.y, vt1 = avt1.x + avt1.y, vt2 = avt2.x + avt2.y, vt3 = avt3.x + avt3.y;
    float vp0 = avp0.x + avp0.y, vp1 = avp1.x + avp1.y, vp2 = avp2.x + avp2.y, vp3 = avp3.x + avp3.y;
    float gx0 = agx0.x + agx0.y, gx1 = agx1.x + agx1.y, gx2 = agx2.x + agx2.y, gx3 = agx3.x + agx3.y;
    float gy0 = agy0.x + agy0.y, gy1 = agy1.x + agy1.y, gy2 = agy2.x + agy2.y, gy3 = agy3.x + agy3.y;

    #pragma unroll
    for (int msk = 1; msk <= 8; msk <<= 1) {
        ut0 += __shfl_xor(ut0, msk);  ut1 += __shfl_xor(ut1, msk);
        ut2 += __shfl_xor(ut2, msk);  ut3 += __shfl_xor(ut3, msk);
        up0 += __shfl_xor(up0, msk);  up1 += __shfl_xor(up1, msk);
        up2 += __shfl_xor(up2, msk);  up3 += __shfl_xor(up3, msk);
        vt0 += __shfl_xor(vt0, msk);  vt1 += __shfl_xor(vt1, msk);
        vt2 += __shfl_xor(vt2, msk);  vt3 += __shfl_xor(vt3, msk);
        vp0 += __shfl_xor(vp0, msk);  vp1 += __shfl_xor(vp1, msk);
        vp2 += __shfl_xor(vp2, msk);  vp3 += __shfl_xor(vp3, msk);
        gx0 += __shfl_xor(gx0, msk);  gx1 += __shfl_xor(gx1, msk);
        gx2 += __shfl_xor(gx2, msk);  gx3 += __shfl_xor(gx3, msk);
        gy0 += __shfl_xor(gy0, msk);  gy1 += __shfl_xor(gy1, msk);
        gy2 += __shfl_xor(gy2, msk);  gy3 += __shfl_xor(gy3, msk);
    }

    // Iplus = sum_{delta>=0} w*delta = up0 - vp0 (identical masked sums)
    // Iminus = Iplus - sum w*delta
    float ip = fmaxf(up0 - vp0, 0.0f);
    float im = fmaxf(ip - ut0 + vt0, 0.0f);

    float Ips = fmaxf(ip, EPSF), Ims = fmaxf(im, EPSF);
    const float third = 1.0f / 3.0f;
    float cp, cn;
    if (ip < im) {
        cp = third;
        cn = fminf(fmaxf(1.0f - (2.0f / 3.0f) * (Ips / Ims), 0.0f), 1.0f);
    } else {
        cp = fminf(fmaxf(1.0f - (2.0f / 3.0f) * (Ims / Ips), 0.0f), 1.0f);
        cn = third;
    }

    // ---- final moments: P = cp*up + cn*(ut-up); out per reference layout ----
    float P0 = cp * up0 + cn * (ut0 - up0), Q0 = cp * vp0 + cn * (vt0 - vp0);
    float P1 = cp * up1 + cn * (ut1 - up1), Q1 = cp * vp1 + cn * (vt1 - vp1);
    float P2 = cp * up2 + cn * (ut2 - up2), Q2 = cp * vp2 + cn * (vt2 - vp2);
    float P3 = cp * up3 + cn * (ut3 - up3), Q3 = cp * vp3 + cn * (vt3 - vp3);

    // memory layout per batch (6 float4): [e, x, x, ebar, xbar, xbar], each (Fx,Fy,Fz,N)
    float4* o4 = (float4*)out + (size_t)b * 6;
    if (sub == 0) {
        o4[0] = make_float4(gx1 + P1, gx2 + P2, gx3 + P3, gx0 + P0);                       // e
    } else if (sub == 1) {
        o4[1] = make_float4(gx1 + 0.5f * (ut1 - P1), gx2 + 0.5f * (ut2 - P2),
                            gx3 + 0.5f * (ut3 - P3), gx0 + 0.5f * (ut0 - P0));             // x
    } else if (sub == 2) {
        o4[2] = make_float4(gx1 + 0.5f * (ut1 - P1), gx2 + 0.5f * (ut2 - P2),
                            gx3 + 0.5f * (ut3 - P3), gx0 + 0.5f * (ut0 - P0));             // x
    } else if (sub == 3) {
        o4[3] = make_float4(gy1 + Q1, gy2 + Q2, gy3 + Q3, gy0 + Q0);                       // ebar
    } else if (sub == 4) {
        o4[4] = make_float4(gy1 + 0.5f * (vt1 - Q1), gy2 + 0.5f * (vt2 - Q2),
                            gy3 + 0.5f * (vt3 - Q3), gy0 + 0.5f * (vt0 - Q0));             // xbar
    } else if (sub == 5) {
        o4[5] = make_float4(gy1 + 0.5f * (vt1 - Q1), gy2 + 0.5f * (vt2 - Q2),
                            gy3 + 0.5f * (vt3 - Q3), gy0 + 0.5f * (vt0 - Q0));             // xbar
    } else if (sub == 6) {
        out[(size_t)B * 24 + b] = sqrtf(fmaxf(ip * im, 0.0f));                             // growth
    }
}

extern "C" void kernel_launch(void* const* d_in, const int* in_sizes, int n_in,
                              void* d_out, int out_size, void* d_ws, size_t ws_size,
                              hipStream_t stream) {
    const float* F4 = (const float*)d_in[0];
    const float* dx = (const float*)d_in[1];
    const float* dy = (const float*)d_in[2];
    const float* dz = (const float*)d_in[3];
    const float* qw = (const float*)d_in[4];
    float* out = (float*)d_out;

    int B = in_sizes[0] / 24;     // (B, 2, 3, 4)
    int ndir = in_sizes[1];       // 800
    float4* ws = (float4*)d_ws;   // B*4 float4 specs (2 MB at B=32768)

    int t1 = 4 * B;
    spec_kernel<<<(t1 + 255) / 256, 256, 0, stream>>>(F4, ws, B);
    int blocks = (B + 15) / 16;   // 16 batch elements per 256-thread block
    box3d_kernel<<<blocks, 256, 0, stream>>>(ws, dx, dy, dz, qw, out, B, ndir);
}